// Round 4
// baseline (577.774 us; speedup 1.0000x reference)
//
#include <hip/hip_runtime.h>

// Problem constants
#define TOKENS 16384      // BATCH(8) * SEQ(2048)
#define DMODEL 1024
#define NHEADS 16
#define HDIM   64

typedef __bf16  bf16x8 __attribute__((ext_vector_type(8)));
typedef ushort  u16x8  __attribute__((ext_vector_type(8)));
typedef float   f32x4  __attribute__((ext_vector_type(4)));

// fp32 -> bf16 (round-half-up; inputs are well-scaled normals, no overflow risk)
__device__ __forceinline__ ushort f2bf(float f) {
    union { float f; unsigned int i; } v; v.f = f;
    return (ushort)((v.i + 0x8000u) >> 16);
}
__device__ __forceinline__ f32x4 mfma16(bf16x8 a, bf16x8 b, f32x4 c) {
    return __builtin_amdgcn_mfma_f32_16x16x32_bf16(a, b, c, 0, 0, 0);
}

// ---------------------------------------------------------------------------
// NT GEMM:  C[m,n] = sum_k A[m,k] * W[n,k] + bias[n]
// fp32 inputs/outputs; bf16 MFMA compute with fp32 accumulation.
// 128x128 tile, BK=32, 256 threads = 4 waves (2x2), each wave 64x64 = 4x4 MFMA
// Staging: fp32 vector load -> convert -> bf16 LDS store.
// ---------------------------------------------------------------------------
#define BM 128
#define BN 128
#define BK 32

struct GemmArgs {
    const float* A[3];
    const float* W[3];
    const float* Bi[3];
    float*       C[3];
};

__global__ __launch_bounds__(256) void gemm_bt_bias(GemmArgs args, int N, int K)
{
    __shared__ __align__(16) ushort As[BM * BK];
    __shared__ __align__(16) ushort Bs[BN * BK];

    const int z = blockIdx.z;
    const float* __restrict__ A  = args.A[z];
    const float* __restrict__ W  = args.W[z];
    const float* __restrict__ Bi = args.Bi[z];
    float*       __restrict__ C  = args.C[z];

    const int tid  = threadIdx.x;
    const int wave = tid >> 6;
    const int lane = tid & 63;
    const int wm = wave >> 1;          // 0..1 row-wave
    const int wn = wave & 1;           // 0..1 col-wave
    const long rowBase = (long)blockIdx.y * BM;
    const int  colBase = blockIdx.x * BN;

    // staging: lane covers row chunk*16 + lane/4, k-elems (lane%4)*8
    const int lrow = lane >> 2;
    const int lk   = (lane & 3) * 8;

    // fragment addressing
    const int fr = lane & 15;          // m (A) / n (B)
    const int fk = (lane >> 4) * 8;    // k offset

    f32x4 acc[4][4];
    #pragma unroll
    for (int i = 0; i < 4; i++)
        #pragma unroll
        for (int j = 0; j < 4; j++)
            acc[i][j] = (f32x4){0.f, 0.f, 0.f, 0.f};

    for (int kt = 0; kt < K; kt += BK) {
        __syncthreads();  // previous tile's ds_reads done before overwrite
        #pragma unroll
        for (int j = 0; j < 2; ++j) {
            const int chunk = wave * 2 + j;                 // 0..7, 16 rows each
            const float* ga = A + (rowBase + chunk * 16 + lrow) * (long)K + kt + lk;
            const float* gw = W + ((long)(colBase + chunk * 16 + lrow)) * K + kt + lk;
            const f32x4 a0 = *(const f32x4*)ga;
            const f32x4 a1 = *(const f32x4*)(ga + 4);
            const f32x4 w0 = *(const f32x4*)gw;
            const f32x4 w1 = *(const f32x4*)(gw + 4);
            u16x8 pa, pw;
            #pragma unroll
            for (int i = 0; i < 4; i++) {
                pa[i]     = f2bf(a0[i]);
                pa[4 + i] = f2bf(a1[i]);
                pw[i]     = f2bf(w0[i]);
                pw[4 + i] = f2bf(w1[i]);
            }
            *(u16x8*)&As[chunk * 16 * BK + lane * 8] = pa;
            *(u16x8*)&Bs[chunk * 16 * BK + lane * 8] = pw;
        }
        __syncthreads();  // staging visible to all waves

        bf16x8 af[4], bf[4];
        #pragma unroll
        for (int i = 0; i < 4; i++)
            af[i] = *(const bf16x8*)&As[(wm * 64 + i * 16 + fr) * BK + fk];
        #pragma unroll
        for (int j = 0; j < 4; j++)
            bf[j] = *(const bf16x8*)&Bs[(wn * 64 + j * 16 + fr) * BK + fk];

        #pragma unroll
        for (int i = 0; i < 4; i++)
            #pragma unroll
            for (int j = 0; j < 4; j++)
                acc[i][j] = mfma16(af[i], bf[j], acc[i][j]);
    }

    // epilogue: C layout col=lane&15, row=(lane>>4)*4+reg; fp32 stores
    const int qd = lane >> 4;
    #pragma unroll
    for (int j = 0; j < 4; j++) {
        const int col = colBase + wn * 64 + j * 16 + fr;
        const float bv = Bi[col];
        #pragma unroll
        for (int i = 0; i < 4; i++) {
            const long r0 = rowBase + wm * 64 + i * 16 + qd * 4;
            #pragma unroll
            for (int r = 0; r < 4; r++)
                C[(r0 + r) * (long)N + col] = acc[i][j][r] + bv;
        }
    }
}

// ---------------------------------------------------------------------------
// Fused per-token attention (16x16 head-gram) + LayerNorm. Pure VALU, fp32.
// One wave per token; 4 tokens per 256-thread block.
// Q and O may ALIAS (in-place): all Q reads complete before O writes.
// ---------------------------------------------------------------------------
#define PADQ 68   // float stride for Qs/Ks rows (16 heads x 64 dims, +4 pad)

__global__ __launch_bounds__(256) void attn_ln_valu(
    const float* Q, const float* __restrict__ Kp,
    const float* __restrict__ V,
    const float* __restrict__ lng, const float* __restrict__ lnb,
    float* O)
{
    __shared__ float Qs[4][16 * PADQ];
    __shared__ float Ks[4][16 * PADQ];
    __shared__ float Vs[4][16 * 64];
    __shared__ __align__(16) float Pt[4][256];      // Pt[g*16+h]
    __shared__ float lg[DMODEL], lb[DMODEL];

    const int tid  = threadIdx.x;
    const int w    = tid >> 6;
    const int lane = tid & 63;
    const long tok  = (long)blockIdx.x * 4 + w;
    const long base = tok * DMODEL;

    // stage LN params (block-shared): 256 threads x 4 floats
    ((f32x4*)lg)[tid] = ((const f32x4*)lng)[tid];
    ((f32x4*)lb)[tid] = ((const f32x4*)lnb)[tid];

    // stage Q,K,V: lane covers head row = lane>>2, dims d0..d0+15
    {
        const int row = lane >> 2;
        const int d0  = (lane & 3) * 16;
        const long go = base + row * HDIM + d0;
        #pragma unroll
        for (int c = 0; c < 4; c++) {
            const f32x4 q = *(const f32x4*)(Q  + go + c * 4);
            const f32x4 k = *(const f32x4*)(Kp + go + c * 4);
            const f32x4 v = *(const f32x4*)(V  + go + c * 4);
            #pragma unroll
            for (int i = 0; i < 4; i++) {
                Qs[w][row * PADQ + d0 + c * 4 + i] = q[i];
                Ks[w][row * PADQ + d0 + c * 4 + i] = k[i];
                Vs[w][row * 64  + d0 + c * 4 + i]  = v[i];
            }
        }
    }
    __syncthreads();

    // energy[h][g] = sum_d Q[h][d]*K[g][d]; lane owns g=lane&15, h=quad*4+r
    const int g  = lane & 15;
    const int hq = lane >> 4;
    float p[4];
    #pragma unroll
    for (int r = 0; r < 4; r++) {
        const int h = hq * 4 + r;
        const float* qrow = &Qs[w][h * PADQ];   // broadcast within 16-lane group
        const float* krow = &Ks[w][g * PADQ];
        float e = 0.f;
        #pragma unroll
        for (int d = 0; d < HDIM; d++) e += qrow[d] * krow[d];

        // softmax over g: reduce across the 16 lanes of this quad-group
        float x = e * 0.03125f;                      // 1/sqrt(1024)
        float mx = x;
        #pragma unroll
        for (int m = 1; m < 16; m <<= 1) mx = fmaxf(mx, __shfl_xor(mx, m, 64));
        float ex = __expf(x - mx);
        float sm = ex;
        #pragma unroll
        for (int m = 1; m < 16; m <<= 1) sm += __shfl_xor(sm, m, 64);
        p[r] = ex / sm;
    }
    // store P transposed: Pt[g*16 + h] (16B-aligned vector store)
    *(f32x4*)&Pt[w][g * 16 + hq * 4] = (f32x4){p[0], p[1], p[2], p[3]};

    __syncthreads();

    // PV: lane <-> d; out[h] = sum_g P[h][g] * V[g][lane]
    float out[NHEADS];
    #pragma unroll
    for (int h = 0; h < NHEADS; h++) out[h] = 0.f;
    #pragma unroll
    for (int gg = 0; gg < 16; gg++) {
        const float vr = Vs[w][gg * 64 + lane];
        const f32x4* prow = (const f32x4*)&Pt[w][gg * 16];
        #pragma unroll
        for (int j = 0; j < 4; j++) {
            const f32x4 pj = prow[j];   // broadcast read, conflict-free
            out[j * 4 + 0] += pj[0] * vr;
            out[j * 4 + 1] += pj[1] * vr;
            out[j * 4 + 2] += pj[2] * vr;
            out[j * 4 + 3] += pj[3] * vr;
        }
    }

    // LayerNorm over 1024 = 16 regs x 64 lanes
    float s1 = 0.f, s2 = 0.f;
    #pragma unroll
    for (int h = 0; h < NHEADS; h++) { s1 += out[h]; s2 += out[h] * out[h]; }
    #pragma unroll
    for (int m = 1; m < 64; m <<= 1) {
        s1 += __shfl_xor(s1, m, 64);
        s2 += __shfl_xor(s2, m, 64);
    }
    const float mu  = s1 * (1.f / DMODEL);
    const float var = s2 * (1.f / DMODEL) - mu * mu;
    const float rstd = rsqrtf(var + 1e-5f);

    #pragma unroll
    for (int h = 0; h < NHEADS; h++) {
        const int i = h * HDIM + lane;
        O[base + i] = (out[h] - mu) * rstd * lg[i] + lb[i];
    }
}

// ---------------------------------------------------------------------------
// launch — ws-size-adaptive chunked pipeline (fp32 everywhere).
// Per chunk of CM tokens: qp,vp in ws (2 * CM*1024 fp32); kp borrows the
// d_out chunk (dead before final GEMM overwrites it); attention output
// in-place over qp.
// ---------------------------------------------------------------------------
extern "C" void kernel_launch(void* const* d_in, const int* in_sizes, int n_in,
                              void* d_out, int out_size, void* d_ws, size_t ws_size,
                              hipStream_t stream)
{
    const float* query = (const float*)d_in[0];
    const float* key   = (const float*)d_in[1];
    const float* value = (const float*)d_in[2];
    const float* Wq = (const float*)d_in[3];
    const float* bq = (const float*)d_in[4];
    const float* Wk = (const float*)d_in[5];
    const float* bk = (const float*)d_in[6];
    const float* Wv = (const float*)d_in[7];
    const float* bv = (const float*)d_in[8];
    const float* lng = (const float*)d_in[9];
    const float* lnb = (const float*)d_in[10];
    const float* Wo = (const float*)d_in[11];
    const float* bo = (const float*)d_in[12];
    float* out = (float*)d_out;
    float* ws  = (float*)d_ws;

    // chunks: need ws_size >= 2 buffers * CM*1024 elems * 4B = CM*8192 bytes
    int NC = 1;
    while (NC < 128 && (size_t)(TOKENS / NC) * 8192 > ws_size) NC <<= 1;
    const int CM = TOKENS / NC;                 // tokens per chunk (mult of 128)
    const size_t CE = (size_t)CM * DMODEL;      // elems per chunk buffer

    float* qp = ws;        // also holds attention output (in-place)
    float* vp = ws + CE;

    for (int c = 0; c < NC; ++c) {
        const size_t off = (size_t)c * CE;
        float* kp = out + off;                  // scratch in d_out chunk

        // 1) fused QKV projections for this chunk (z picks q/k/v)
        GemmArgs g1;
        g1.A[0] = query + off; g1.A[1] = key + off; g1.A[2] = value + off;
        g1.W[0] = Wq;    g1.W[1] = Wk;  g1.W[2] = Wv;
        g1.Bi[0] = bq;   g1.Bi[1] = bk; g1.Bi[2] = bv;
        g1.C[0] = qp;    g1.C[1] = kp;  g1.C[2] = vp;
        gemm_bt_bias<<<dim3(DMODEL / BN, CM / BM, 3), 256, 0, stream>>>(
            g1, DMODEL, DMODEL);

        // 2) per-token attention + LayerNorm (output in-place over qp)
        attn_ln_valu<<<CM / 4, 256, 0, stream>>>(qp, kp, vp, lng, lnb, qp);

        // 3) output projection -> d_out chunk (overwrites kp scratch)
        GemmArgs g2;
        g2.A[0] = g2.A[1] = g2.A[2] = qp;
        g2.W[0] = g2.W[1] = g2.W[2] = Wo;
        g2.Bi[0] = g2.Bi[1] = g2.Bi[2] = bo;
        g2.C[0] = g2.C[1] = g2.C[2] = out + off;
        gemm_bt_bias<<<dim3(DMODEL / BN, CM / BM, 1), 256, 0, stream>>>(
            g2, DMODEL, DMODEL);
    }
}